// Round 1
// baseline (3183.412 us; speedup 1.0000x reference)
//
#include <hip/hip_runtime.h>
#include <hip/hip_bf16.h>
#include <math.h>

#define NN 100000
#define NE 1600000
#define NR 8
#define DD 64
#define DDR 64

// ---- order-preserving float<->uint encoding for atomicMax (0 == -inf-ish floor) ----
__device__ __forceinline__ unsigned enc_f(float f) {
    unsigned u = __float_as_uint(f);
    return (u & 0x80000000u) ? ~u : (u | 0x80000000u);
}
__device__ __forceinline__ float dec_f(unsigned u) {
    return (u & 0x80000000u) ? __uint_as_float(u & 0x7FFFFFFFu) : __uint_as_float(~u);
}

// ---- Kernel A: per-edge attention logits + segment max ----
// one 64-lane wave per edge; lane k computes output element k of both matvecs
__global__ void k_att(const float* __restrict__ emb, const float* __restrict__ rel,
                      const float* __restrict__ WR, const int* __restrict__ src,
                      const int* __restrict__ dst, const int* __restrict__ et,
                      float* __restrict__ att, unsigned* __restrict__ mkey)
{
    int e = (int)((blockIdx.x * blockDim.x + threadIdx.x) >> 6);
    int lane = threadIdx.x & 63;
    if (e >= NE) return;
    int s = src[e], d = dst[e], r = et[e];
    const float* __restrict__ es = emb + (long)s * DD;
    const float* __restrict__ eh = emb + (long)d * DD;
    const float* __restrict__ w  = WR + r * (DD * DDR) + lane;  // w[dd*DDR]
    float at = 0.f, ah = 0.f;
#pragma unroll 8
    for (int dd = 0; dd < DD; ++dd) {
        float ws = w[dd * DDR];          // coalesced across lanes, L2-resident
        at = fmaf(es[dd], ws, at);       // uniform-address broadcast loads
        ah = fmaf(eh[dd], ws, ah);
    }
    float term = at * tanhf(ah + rel[r * DDR + lane]);
#pragma unroll
    for (int off = 32; off; off >>= 1) term += __shfl_xor(term, off);
    if (lane == 0) {
        att[e] = term;
        atomicMax(mkey + d, enc_f(term));
    }
}

// ---- Kernel B: ex = exp(att - m[dst]); segment sum ----
__global__ void k_expsum(const int* __restrict__ dst, float* __restrict__ att,
                         const unsigned* __restrict__ mkey, float* __restrict__ ssum)
{
    int e = blockIdx.x * blockDim.x + threadIdx.x;
    if (e >= NE) return;
    int d = dst[e];
    float ex = expf(att[e] - dec_f(mkey[d]));
    att[e] = ex;
    atomicAdd(ssum + d, ex);
}

// ---- Kernel D: layer-0 aggregation; also finalizes a[e] = ex/ssum in att ----
__global__ void k_agg0(const float* __restrict__ emb, const int* __restrict__ src,
                       const int* __restrict__ dst, float* __restrict__ att,
                       const float* __restrict__ ssum, float* __restrict__ Nh)
{
    int e = (int)((blockIdx.x * blockDim.x + threadIdx.x) >> 6);
    int lane = threadIdx.x & 63;
    if (e >= NE) return;
    int s = src[e], d = dst[e];
    float a = att[e] / ssum[d];          // all lanes read before lane0 writes
    if (lane == 0) att[e] = a;           // persist normalized a for layer 1
    float v = emb[(long)s * DD + lane] * a;
    atomicAdd(Nh + (long)d * DD + lane, v);
}

// ---- Kernel E: layer-0 node update; writes ego (cols 0..64) and h1 (cols 64..96) ----
__global__ void k_node0(const float* __restrict__ emb, const float* __restrict__ Nh,
                        const float* __restrict__ W1, const float* __restrict__ b1,
                        const float* __restrict__ W2, const float* __restrict__ b2,
                        float* __restrict__ out)
{
    int node = (int)((blockIdx.x * blockDim.x + threadIdx.x) >> 6);
    int lane = threadIdx.x & 63;
    if (node >= NN) return;
    const float* __restrict__ x  = emb + (long)node * DD;
    const float* __restrict__ nh = Nh + (long)node * DD;
    int j = lane & 31;
    const float* __restrict__ W = (lane < 32) ? (W1 + j * DD) : (W2 + j * DD);
    float acc = 0.f;
#pragma unroll 8
    for (int dd = 0; dd < DD; ++dd) {
        float xv = x[dd], nv = nh[dd];
        float v = (lane < 32) ? (xv + nv) : (xv * nv);
        acc = fmaf(v, W[dd], acc);
    }
    acc += (lane < 32) ? b1[j] : b2[j];
    acc = (acc >= 0.f) ? acc : 0.01f * acc;          // leaky_relu
    float other = __shfl_down(acc, 32);              // out2[j] to lane j
    float h = acc + other;                           // valid for lane < 32
    float ss = h * h;
#pragma unroll
    for (int off = 16; off; off >>= 1) ss += __shfl_xor(ss, off);  // within 32-group
    float nrm = sqrtf(ss);
    float hn = h / fmaxf(nrm, 1e-12f);
    out[(long)node * 112 + lane] = x[lane];          // ego copy
    if (lane < 32) out[(long)node * 112 + 64 + j] = hn;
}

// ---- Kernel F: layer-1 aggregation (h1 lives in d_out cols 64..96) ----
__global__ void k_agg1(const float* __restrict__ out, const int* __restrict__ src,
                       const int* __restrict__ dst, const float* __restrict__ att,
                       float* __restrict__ Nh1)
{
    int idx = blockIdx.x * blockDim.x + threadIdx.x;
    int e = idx >> 5;
    int j = idx & 31;
    if (e >= NE) return;
    int s = src[e], d = dst[e];
    float a = att[e];
    float v = out[(long)s * 112 + 64 + j] * a;
    atomicAdd(Nh1 + (long)d * 32 + j, v);
}

// ---- Kernel G: layer-1 node update; writes h2 (cols 96..112) ----
__global__ void k_node1(const float* __restrict__ outbuf, const float* __restrict__ Nh1,
                        const float* __restrict__ W1, const float* __restrict__ b1,
                        const float* __restrict__ W2, const float* __restrict__ b2,
                        float* __restrict__ out)
{
    int t = blockIdx.x * blockDim.x + threadIdx.x;
    int node = t >> 5;                  // 32 lanes per node (2 nodes per wave)
    int lane = t & 31;
    if (node >= NN) return;
    const float* __restrict__ x  = outbuf + (long)node * 112 + 64;  // h1 row
    const float* __restrict__ nh = Nh1 + (long)node * 32;
    int j = lane & 15;
    const float* __restrict__ W = (lane < 16) ? (W1 + j * 32) : (W2 + j * 32);
    float acc = 0.f;
#pragma unroll 8
    for (int dd = 0; dd < 32; ++dd) {
        float xv = x[dd], nv = nh[dd];
        float v = (lane < 16) ? (xv + nv) : (xv * nv);
        acc = fmaf(v, W[dd], acc);
    }
    acc += (lane < 16) ? b1[j] : b2[j];
    acc = (acc >= 0.f) ? acc : 0.01f * acc;
    float other = __shfl_down(acc, 16, 32);          // stay within 32-lane subgroup
    float h = acc + other;                           // valid for lane < 16
    float ss = h * h;
#pragma unroll
    for (int off = 8; off; off >>= 1) ss += __shfl_xor(ss, off);   // within 16-group
    float nrm = sqrtf(ss);
    float hn = h / fmaxf(nrm, 1e-12f);
    if (lane < 16) out[(long)node * 112 + 96 + j] = hn;
}

extern "C" void kernel_launch(void* const* d_in, const int* in_sizes, int n_in,
                              void* d_out, int out_size, void* d_ws, size_t ws_size,
                              hipStream_t stream) {
    const float* emb  = (const float*)d_in[0];
    const float* rel  = (const float*)d_in[1];
    const float* WR   = (const float*)d_in[2];
    const float* W1_0 = (const float*)d_in[3];
    const float* b1_0 = (const float*)d_in[4];
    const float* W2_0 = (const float*)d_in[5];
    const float* b2_0 = (const float*)d_in[6];
    const float* W1_1 = (const float*)d_in[7];
    const float* b1_1 = (const float*)d_in[8];
    const float* W2_1 = (const float*)d_in[9];
    const float* b2_1 = (const float*)d_in[10];
    const int*   src  = (const int*)d_in[11];
    const int*   dst  = (const int*)d_in[12];
    const int*   et   = (const int*)d_in[13];
    float* out = (float*)d_out;

    // workspace layout (floats): [mkey N][ssum N][Nh0 64N][Nh1 32N][att E]
    unsigned* mkey = (unsigned*)d_ws;
    float* ssum = (float*)d_ws + NN;
    float* Nh0  = (float*)d_ws + 2 * NN;
    float* Nh1  = (float*)d_ws + (2 + DD) * NN;
    float* att  = (float*)d_ws + (2 + DD + 32) * NN;

    // zero mkey/ssum/Nh0/Nh1 (att fully overwritten)
    hipMemsetAsync(d_ws, 0, (size_t)(2 + DD + 32) * NN * sizeof(float), stream);

    k_att<<<dim3((NE * 64 + 255) / 256), dim3(256), 0, stream>>>(
        emb, rel, WR, src, dst, et, att, mkey);
    k_expsum<<<dim3((NE + 255) / 256), dim3(256), 0, stream>>>(dst, att, mkey, ssum);
    k_agg0<<<dim3((NE * 64 + 255) / 256), dim3(256), 0, stream>>>(
        emb, src, dst, att, ssum, Nh0);
    k_node0<<<dim3((NN * 64 + 255) / 256), dim3(256), 0, stream>>>(
        emb, Nh0, W1_0, b1_0, W2_0, b2_0, out);
    k_agg1<<<dim3((NE * 32 + 255) / 256), dim3(256), 0, stream>>>(
        out, src, dst, att, Nh1);
    k_node1<<<dim3((NN * 32 + 255) / 256), dim3(256), 0, stream>>>(
        out, Nh1, W1_1, b1_1, W2_1, b2_1, out);
}